// Round 5
// baseline (361.807 us; speedup 1.0000x reference)
//
#include <hip/hip_runtime.h>
#include <hip/hip_bf16.h>
#include <stdint.h>

#define D_DIM 512
#define B_CTX 512
#define M_MEM 65536
#define BM 128
#define BB 128
#define BK 32
#define LDSPAD 40            // 80 B row pitch: 16B-aligned, frag reads 2-way (free)
#define NTILE (M_MEM / BM)   // 512
#define DELTA_COS 2.5e-3f    // ~35 sigma of bf16 cosine noise (7.1e-5), scale-invariant

typedef __attribute__((ext_vector_type(8))) short short8;   // 8 bf16 (4 VGPR)
typedef __attribute__((ext_vector_type(4))) float floatx4;  // MFMA accumulator

__device__ __forceinline__ uint32_t f32_order(float s) {    // monotone f32->u32
    uint32_t u = __float_as_uint(s);
    return (u & 0x80000000u) ? ~u : (u | 0x80000000u);
}
__device__ __forceinline__ float f32_unorder(uint32_t v) {
    uint32_t u = (v & 0x80000000u) ? (v & 0x7FFFFFFFu) : ~v;
    return __uint_as_float(u);
}
__device__ __forceinline__ uint32_t pack_bf16_rtn(float a, float b) {
    uint32_t ua = __float_as_uint(a) + 0x8000u;
    uint32_t ub = __float_as_uint(b) + 0x8000u;
    return (ua >> 16) | (ub & 0xFFFF0000u);
}

// ---------------- kernel 0: dtype probe ----------------
__global__ void detect_init(const uint32_t* __restrict__ mem_raw,
                            uint32_t* __restrict__ flag) {
    __shared__ int cnt;
    if (threadIdx.x == 0) cnt = 0;
    __syncthreads();
    int s = 0;
    #pragma unroll
    for (int i = 0; i < 8; ++i) {
        uint32_t u = mem_raw[threadIdx.x * 8 + i];
        uint32_t e = (u >> 7) & 0xFFu;   // exponent of LOW bf16 half
        s += (e >= 96u && e <= 144u) ? 1 : 0;
    }
    atomicAdd(&cnt, s);
    __syncthreads();
    if (threadIdx.x == 0) *flag = (cnt > 256) ? 1u : 0u;   // 1 == bf16 inputs
}

// ---------------- kernel 1: bf16 MFMA approx scores + per-tile max ----------------
__global__ __launch_bounds__(256) void score_phase1(const void* __restrict__ ctxv,
                                                    const void* __restrict__ memv,
                                                    const uint32_t* __restrict__ flag,
                                                    uint32_t* __restrict__ tmax) {
    __shared__ __align__(16) uint16_t at[BM][LDSPAD];   // memory tile (bf16 bits)
    __shared__ __align__(16) uint16_t bt[BB][LDSPAD];   // context tile
    __shared__ uint32_t s_best[BB];
    __shared__ float s_nsq[BM];

    const int t    = threadIdx.x;
    const int b0   = blockIdx.x * BB;
    const int m0   = blockIdx.y * BM;
    const int lane = t & 63;
    const int w    = t >> 6;
    const int wm   = w >> 1;
    const int wb   = w & 1;
    const int quad = lane >> 4;
    const int l15  = lane & 15;
    const int srow = t >> 2;
    const int scol = (t & 3) * 8;

    if (t < BB) s_best[t] = 0u;

    floatx4 acc[4][4];
    #pragma unroll
    for (int i = 0; i < 4; ++i)
        #pragma unroll
        for (int j = 0; j < 4; ++j)
            acc[i][j] = (floatx4){0.f, 0.f, 0.f, 0.f};

    float nsq0 = 0.f, nsq1 = 0.f;          // mem-row norms (rows srow, srow+64)
    const bool isbf = (*flag != 0u);

    for (int k0 = 0; k0 < D_DIM; k0 += BK) {
        __syncthreads();
        if (isbf) {
            const uint16_t* mp = (const uint16_t*)memv;
            const uint16_t* cp = (const uint16_t*)ctxv;
            uint4 va0 = *(const uint4*)(mp + (size_t)(m0 + srow) * D_DIM + k0 + scol);
            uint4 va1 = *(const uint4*)(mp + (size_t)(m0 + srow + 64) * D_DIM + k0 + scol);
            uint4 vb0 = *(const uint4*)(cp + (size_t)(b0 + srow) * D_DIM + k0 + scol);
            uint4 vb1 = *(const uint4*)(cp + (size_t)(b0 + srow + 64) * D_DIM + k0 + scol);
            *(uint4*)&at[srow][scol] = va0;
            *(uint4*)&at[srow + 64][scol] = va1;
            *(uint4*)&bt[srow][scol] = vb0;
            *(uint4*)&bt[srow + 64][scol] = vb1;
            uint32_t wa0[4] = {va0.x, va0.y, va0.z, va0.w};
            uint32_t wa1[4] = {va1.x, va1.y, va1.z, va1.w};
            #pragma unroll
            for (int i = 0; i < 4; ++i) {
                float a = __uint_as_float(wa0[i] << 16);
                float b = __uint_as_float(wa0[i] & 0xFFFF0000u);
                nsq0 = fmaf(a, a, nsq0); nsq0 = fmaf(b, b, nsq0);
                float c = __uint_as_float(wa1[i] << 16);
                float d = __uint_as_float(wa1[i] & 0xFFFF0000u);
                nsq1 = fmaf(c, c, nsq1); nsq1 = fmaf(d, d, nsq1);
            }
        } else {
            const float* mp = (const float*)memv;
            const float* cp = (const float*)ctxv;
            const float4* pa0 = (const float4*)(mp + (size_t)(m0 + srow) * D_DIM + k0 + scol);
            const float4* pa1 = (const float4*)(mp + (size_t)(m0 + srow + 64) * D_DIM + k0 + scol);
            const float4* pb0 = (const float4*)(cp + (size_t)(b0 + srow) * D_DIM + k0 + scol);
            const float4* pb1 = (const float4*)(cp + (size_t)(b0 + srow + 64) * D_DIM + k0 + scol);
            float4 a0 = pa0[0], a1 = pa0[1], a2 = pa1[0], a3 = pa1[1];
            float4 c0 = pb0[0], c1 = pb0[1], c2 = pb1[0], c3 = pb1[1];
            uint4 va0 = {pack_bf16_rtn(a0.x, a0.y), pack_bf16_rtn(a0.z, a0.w),
                         pack_bf16_rtn(a1.x, a1.y), pack_bf16_rtn(a1.z, a1.w)};
            uint4 va1 = {pack_bf16_rtn(a2.x, a2.y), pack_bf16_rtn(a2.z, a2.w),
                         pack_bf16_rtn(a3.x, a3.y), pack_bf16_rtn(a3.z, a3.w)};
            uint4 vb0 = {pack_bf16_rtn(c0.x, c0.y), pack_bf16_rtn(c0.z, c0.w),
                         pack_bf16_rtn(c1.x, c1.y), pack_bf16_rtn(c1.z, c1.w)};
            uint4 vb1 = {pack_bf16_rtn(c2.x, c2.y), pack_bf16_rtn(c2.z, c2.w),
                         pack_bf16_rtn(c3.x, c3.y), pack_bf16_rtn(c3.z, c3.w)};
            *(uint4*)&at[srow][scol] = va0;
            *(uint4*)&at[srow + 64][scol] = va1;
            *(uint4*)&bt[srow][scol] = vb0;
            *(uint4*)&bt[srow + 64][scol] = vb1;
            nsq0 = fmaf(a0.x, a0.x, nsq0); nsq0 = fmaf(a0.y, a0.y, nsq0);
            nsq0 = fmaf(a0.z, a0.z, nsq0); nsq0 = fmaf(a0.w, a0.w, nsq0);
            nsq0 = fmaf(a1.x, a1.x, nsq0); nsq0 = fmaf(a1.y, a1.y, nsq0);
            nsq0 = fmaf(a1.z, a1.z, nsq0); nsq0 = fmaf(a1.w, a1.w, nsq0);
            nsq1 = fmaf(a2.x, a2.x, nsq1); nsq1 = fmaf(a2.y, a2.y, nsq1);
            nsq1 = fmaf(a2.z, a2.z, nsq1); nsq1 = fmaf(a2.w, a2.w, nsq1);
            nsq1 = fmaf(a3.x, a3.x, nsq1); nsq1 = fmaf(a3.y, a3.y, nsq1);
            nsq1 = fmaf(a3.w, a3.w, nsq1); nsq1 = fmaf(a3.z, a3.z, nsq1);
        }
        __syncthreads();

        short8 af[4], bg[4];
        #pragma unroll
        for (int i = 0; i < 4; ++i)
            af[i] = *(const short8*)&at[wm * 64 + i * 16 + l15][quad * 8];
        #pragma unroll
        for (int j = 0; j < 4; ++j)
            bg[j] = *(const short8*)&bt[wb * 64 + j * 16 + l15][quad * 8];

        #pragma unroll
        for (int i = 0; i < 4; ++i)
            #pragma unroll
            for (int j = 0; j < 4; ++j)
                acc[i][j] = __builtin_amdgcn_mfma_f32_16x16x32_bf16(af[i], bg[j], acc[i][j], 0, 0, 0);
    }

    // reduce nsq across the 4 consecutive lanes sharing a row (same wave)
    nsq0 += __shfl_xor(nsq0, 1, 64); nsq0 += __shfl_xor(nsq0, 2, 64);
    nsq1 += __shfl_xor(nsq1, 1, 64); nsq1 += __shfl_xor(nsq1, 2, 64);
    __syncthreads();
    if ((t & 3) == 0) { s_nsq[srow] = nsq0; s_nsq[srow + 64] = nsq1; }
    __syncthreads();

    // epilogue: scale by invnorm, per-(b, mtile) max.  C/D: row=quad*4+r, col=l15
    float invn[4][4];
    #pragma unroll
    for (int i = 0; i < 4; ++i)
        #pragma unroll
        for (int r = 0; r < 4; ++r)
            invn[i][r] = rsqrtf(fmaxf(s_nsq[wm * 64 + i * 16 + quad * 4 + r], 1e-12f));

    #pragma unroll
    for (int j = 0; j < 4; ++j) {
        uint32_t best = 0u;
        #pragma unroll
        for (int i = 0; i < 4; ++i)
            #pragma unroll
            for (int r = 0; r < 4; ++r) {
                uint32_t k = f32_order(acc[i][j][r] * invn[i][r]);
                best = k > best ? k : best;
            }
        atomicMax(&s_best[wb * 64 + j * 16 + l15], best);
    }
    __syncthreads();
    if (t < BB) tmax[(size_t)(b0 + t) * NTILE + blockIdx.y] = s_best[t];
}

// ---------------- kernel 2: exact fp64 rescore of candidate tiles + gather ----------------
__global__ __launch_bounds__(256) void phase2(const void* __restrict__ ctxv,
                                              const void* __restrict__ memv,
                                              const uint32_t* __restrict__ flag,
                                              const uint32_t* __restrict__ tmax,
                                              void* __restrict__ outv) {
    __shared__ float s_ctx[D_DIM];
    __shared__ int s_list[NTILE];
    __shared__ int s_cnt;
    __shared__ uint32_t s_red[4];
    __shared__ float s_cn[4];
    __shared__ double s_ws[4];
    __shared__ int s_wm[4];
    __shared__ int s_bestm;

    const int b = blockIdx.x;
    const int t = threadIdx.x;
    const int lane = t & 63;
    const int w = t >> 6;
    const bool isbf = (*flag != 0u);

    if (t == 0) s_cnt = 0;
    if (isbf) {
        if (t < 64) {
            const uint16_t* cp = (const uint16_t*)ctxv + (size_t)b * D_DIM + t * 8;
            uint4 v = *(const uint4*)cp;
            uint32_t ww[4] = {v.x, v.y, v.z, v.w};
            #pragma unroll
            for (int i = 0; i < 4; ++i) {
                s_ctx[t * 8 + 2 * i]     = __uint_as_float(ww[i] << 16);
                s_ctx[t * 8 + 2 * i + 1] = __uint_as_float(ww[i] & 0xFFFF0000u);
            }
        }
    } else {
        if (t < 128)
            ((float4*)s_ctx)[t] = ((const float4*)((const float*)ctxv + (size_t)b * D_DIM))[t];
    }
    __syncthreads();

    // ctx norm (for scale-invariant rescan margin)
    float cs = s_ctx[t] * s_ctx[t] + s_ctx[t + 256] * s_ctx[t + 256];
    #pragma unroll
    for (int o = 32; o; o >>= 1) cs += __shfl_xor(cs, o, 64);
    if (lane == 0) s_cn[w] = cs;

    // block max over this b's 512 tile keys
    const uint32_t* tk = tmax + (size_t)b * NTILE;
    uint32_t k0 = tk[t], k1 = tk[t + 256];
    uint32_t km = k0 > k1 ? k0 : k1;
    #pragma unroll
    for (int o = 32; o; o >>= 1) { uint32_t ot = __shfl_xor(km, o, 64); km = ot > km ? ot : km; }
    if (lane == 0) s_red[w] = km;
    __syncthreads();
    uint32_t kbest = s_red[0];
    #pragma unroll
    for (int i = 1; i < 4; ++i) kbest = s_red[i] > kbest ? s_red[i] : kbest;
    const float cnorm = sqrtf(s_cn[0] + s_cn[1] + s_cn[2] + s_cn[3]);
    const uint32_t keyT = f32_order(f32_unorder(kbest) - DELTA_COS * cnorm);

    if (k0 >= keyT) { int idx = atomicAdd(&s_cnt, 1); s_list[idx] = t; }
    if (k1 >= keyT) { int idx = atomicAdd(&s_cnt, 1); s_list[idx] = t + 256; }
    __syncthreads();
    const int cnt = s_cnt;

    double bs = -1.0e300; int bm = 0x7FFFFFFF;
    for (int li = 0; li < cnt; ++li) {
        const int tile = s_list[li];
        for (int r = w; r < BM; r += 4) {
            const int m = tile * BM + r;
            double dot = 0.0, nsq = 0.0;
            if (isbf) {
                const uint16_t* mp = (const uint16_t*)memv + (size_t)m * D_DIM;
                #pragma unroll
                for (int j = 0; j < 8; ++j) {
                    float x = __uint_as_float(((uint32_t)mp[lane + 64 * j]) << 16);
                    float c = s_ctx[lane + 64 * j];
                    dot += (double)x * (double)c;
                    nsq += (double)x * (double)x;
                }
            } else {
                const float* mp = (const float*)memv + (size_t)m * D_DIM;
                #pragma unroll
                for (int j = 0; j < 8; ++j) {
                    float x = mp[lane + 64 * j];
                    float c = s_ctx[lane + 64 * j];
                    dot += (double)x * (double)c;
                    nsq += (double)x * (double)x;
                }
            }
            #pragma unroll
            for (int o = 32; o; o >>= 1) {
                dot += __shfl_xor(dot, o, 64);
                nsq += __shfl_xor(nsq, o, 64);
            }
            double s = dot / sqrt(fmax(nsq, 1e-300));
            if (s > bs || (s == bs && m < bm)) { bs = s; bm = m; }
        }
    }
    if (lane == 0) { s_ws[w] = bs; s_wm[w] = bm; }
    __syncthreads();
    if (t == 0) {
        double best = s_ws[0]; int bmm = s_wm[0];
        #pragma unroll
        for (int i = 1; i < 4; ++i)
            if (s_ws[i] > best || (s_ws[i] == best && s_wm[i] < bmm)) { best = s_ws[i]; bmm = s_wm[i]; }
        s_bestm = bmm;
    }
    __syncthreads();
    const int mbest = s_bestm;
    if (isbf) {
        if (t < 64)
            ((uint4*)((uint16_t*)outv + (size_t)b * D_DIM))[t] =
                ((const uint4*)((const uint16_t*)memv + (size_t)mbest * D_DIM))[t];
    } else {
        if (t < 128)
            ((float4*)((float*)outv + (size_t)b * D_DIM))[t] =
                ((const float4*)((const float*)memv + (size_t)mbest * D_DIM))[t];
    }
}

extern "C" void kernel_launch(void* const* d_in, const int* in_sizes, int n_in,
                              void* d_out, int out_size, void* d_ws, size_t ws_size,
                              hipStream_t stream) {
    const void* ctx = d_in[0];
    const void* mem = d_in[1];
    if (in_sizes[0] > in_sizes[1]) { ctx = d_in[1]; mem = d_in[0]; }  // ctx is smaller

    // ws: [0, 1MB) tmax u32[B_CTX][NTILE] | [1MB, +4) flag
    uint32_t* tmax = (uint32_t*)d_ws;
    uint32_t* flag = (uint32_t*)((char*)d_ws + (size_t)B_CTX * NTILE * 4);

    detect_init<<<1, 64, 0, stream>>>((const uint32_t*)mem, flag);
    dim3 grid(B_CTX / BB, M_MEM / BM);
    score_phase1<<<grid, 256, 0, stream>>>(ctx, mem, flag, tmax);
    phase2<<<B_CTX, 256, 0, stream>>>(ctx, mem, flag, tmax, d_out);
}

// Round 6
// 354.072 us; speedup vs baseline: 1.0218x; 1.0218x over previous
//
#include <hip/hip_runtime.h>
#include <hip/hip_bf16.h>
#include <stdint.h>

#define D_DIM 512
#define B_CTX 512
#define M_MEM 65536
#define BM 128
#define BB 128
#define BK 32
#define LDSPAD 40            // 80 B row pitch: 16B-aligned, frag reads 2-way (free)
#define NTILE (M_MEM / BM)   // 512
#define DELTA_COS 2.5e-3f    // ~35 sigma of bf16 cosine noise, scale-invariant

typedef __attribute__((ext_vector_type(8))) short short8;   // 8 bf16 (4 VGPR)
typedef __attribute__((ext_vector_type(4))) float floatx4;  // MFMA accumulator

__device__ __forceinline__ uint32_t f32_order(float s) {    // monotone f32->u32
    uint32_t u = __float_as_uint(s);
    return (u & 0x80000000u) ? ~u : (u | 0x80000000u);
}
__device__ __forceinline__ float f32_unorder(uint32_t v) {
    uint32_t u = (v & 0x80000000u) ? (v & 0x7FFFFFFFu) : ~v;
    return __uint_as_float(u);
}
__device__ __forceinline__ uint32_t pack_bf16_rtn(float a, float b) {
    uint32_t ua = __float_as_uint(a) + 0x8000u;
    uint32_t ub = __float_as_uint(b) + 0x8000u;
    return (ua >> 16) | (ub & 0xFFFF0000u);
}

// ---------------- kernel 0: dtype probe ----------------
__global__ void detect_init(const uint32_t* __restrict__ mem_raw,
                            uint32_t* __restrict__ flag) {
    __shared__ int cnt;
    if (threadIdx.x == 0) cnt = 0;
    __syncthreads();
    int s = 0;
    #pragma unroll
    for (int i = 0; i < 8; ++i) {
        uint32_t u = mem_raw[threadIdx.x * 8 + i];
        uint32_t e = (u >> 7) & 0xFFu;   // exponent of LOW bf16 half
        s += (e >= 96u && e <= 144u) ? 1 : 0;
    }
    atomicAdd(&cnt, s);
    __syncthreads();
    if (threadIdx.x == 0) *flag = (cnt > 256) ? 1u : 0u;   // 1 == bf16 inputs
}

// ---------------- kernel 1: pre-convert fp32->bf16 + per-row inv norms ----------------
__global__ __launch_bounds__(256) void convert_norms(const void* __restrict__ memv,
                                                     const void* __restrict__ ctxv,
                                                     const uint32_t* __restrict__ flag,
                                                     uint4* __restrict__ mem_bf,
                                                     uint4* __restrict__ ctx_bf,
                                                     float* __restrict__ inv_norm) {
    const int w = threadIdx.x >> 6, lane = threadIdx.x & 63;
    const int row = blockIdx.x * 4 + w;
    const bool isbf = (*flag != 0u);
    if (row < M_MEM) {
        float ns = 0.f;
        if (isbf) {
            uint4 v = *((const uint4*)((const uint16_t*)memv + (size_t)row * D_DIM) + lane);
            uint32_t ww[4] = {v.x, v.y, v.z, v.w};
            #pragma unroll
            for (int i = 0; i < 4; ++i) {
                float a = __uint_as_float(ww[i] << 16);
                float b = __uint_as_float(ww[i] & 0xFFFF0000u);
                ns = fmaf(a, a, ns); ns = fmaf(b, b, ns);
            }
            // no copy: phase1 reads the raw bf16 input directly
        } else {
            const float4* p = (const float4*)((const float*)memv + (size_t)row * D_DIM) + lane * 2;
            float4 a = p[0], b = p[1];
            uint4 pk = {pack_bf16_rtn(a.x, a.y), pack_bf16_rtn(a.z, a.w),
                        pack_bf16_rtn(b.x, b.y), pack_bf16_rtn(b.z, b.w)};
            mem_bf[(size_t)row * 64 + lane] = pk;
            ns = fmaf(a.x, a.x, ns); ns = fmaf(a.y, a.y, ns);
            ns = fmaf(a.z, a.z, ns); ns = fmaf(a.w, a.w, ns);
            ns = fmaf(b.x, b.x, ns); ns = fmaf(b.y, b.y, ns);
            ns = fmaf(b.z, b.z, ns); ns = fmaf(b.w, b.w, ns);
        }
        #pragma unroll
        for (int o = 32; o; o >>= 1) ns += __shfl_xor(ns, o, 64);
        if (lane == 0) inv_norm[row] = rsqrtf(fmaxf(ns, 1e-12f));
    } else {
        const int cr = row - M_MEM;   // < B_CTX
        if (!isbf) {
            const float4* p = (const float4*)((const float*)ctxv + (size_t)cr * D_DIM) + lane * 2;
            float4 a = p[0], b = p[1];
            uint4 pk = {pack_bf16_rtn(a.x, a.y), pack_bf16_rtn(a.z, a.w),
                        pack_bf16_rtn(b.x, b.y), pack_bf16_rtn(b.z, b.w)};
            ctx_bf[(size_t)cr * 64 + lane] = pk;
        }
    }
}

// ---------------- kernel 2a: bf16 MFMA scores + per-tile max (pre-converted) ----------------
__global__ __launch_bounds__(256) void score_phase1_pre(const void* __restrict__ ctx_raw,
                                                        const void* __restrict__ mem_raw,
                                                        const uint16_t* __restrict__ ctx_bf,
                                                        const uint16_t* __restrict__ mem_bf,
                                                        const uint32_t* __restrict__ flag,
                                                        const float* __restrict__ inv_norm,
                                                        uint32_t* __restrict__ tmax) {
    __shared__ __align__(16) uint16_t at[BM][LDSPAD];
    __shared__ __align__(16) uint16_t bt[BB][LDSPAD];
    __shared__ uint32_t s_best[BB];

    const int t    = threadIdx.x;
    const int b0   = blockIdx.x * BB;
    const int m0   = blockIdx.y * BM;
    const int lane = t & 63;
    const int w    = t >> 6;
    const int wm   = w >> 1;
    const int wb   = w & 1;
    const int quad = lane >> 4;
    const int l15  = lane & 15;
    const int srow = t >> 2;
    const int scol = (t & 3) * 8;

    const bool isbf = (*flag != 0u);
    const uint16_t* A  = isbf ? (const uint16_t*)mem_raw : mem_bf;  // wave-uniform select
    const uint16_t* Bc = isbf ? (const uint16_t*)ctx_raw : ctx_bf;

    if (t < BB) s_best[t] = 0u;

    floatx4 acc[4][4];
    #pragma unroll
    for (int i = 0; i < 4; ++i)
        #pragma unroll
        for (int j = 0; j < 4; ++j)
            acc[i][j] = (floatx4){0.f, 0.f, 0.f, 0.f};

    for (int k0 = 0; k0 < D_DIM; k0 += BK) {
        __syncthreads();
        uint4 va0 = *(const uint4*)(A + (size_t)(m0 + srow) * D_DIM + k0 + scol);
        uint4 va1 = *(const uint4*)(A + (size_t)(m0 + srow + 64) * D_DIM + k0 + scol);
        uint4 vb0 = *(const uint4*)(Bc + (size_t)(b0 + srow) * D_DIM + k0 + scol);
        uint4 vb1 = *(const uint4*)(Bc + (size_t)(b0 + srow + 64) * D_DIM + k0 + scol);
        *(uint4*)&at[srow][scol] = va0;
        *(uint4*)&at[srow + 64][scol] = va1;
        *(uint4*)&bt[srow][scol] = vb0;
        *(uint4*)&bt[srow + 64][scol] = vb1;
        __syncthreads();

        short8 af[4], bg[4];
        #pragma unroll
        for (int i = 0; i < 4; ++i)
            af[i] = *(const short8*)&at[wm * 64 + i * 16 + l15][quad * 8];
        #pragma unroll
        for (int j = 0; j < 4; ++j)
            bg[j] = *(const short8*)&bt[wb * 64 + j * 16 + l15][quad * 8];

        #pragma unroll
        for (int i = 0; i < 4; ++i)
            #pragma unroll
            for (int j = 0; j < 4; ++j)
                acc[i][j] = __builtin_amdgcn_mfma_f32_16x16x32_bf16(af[i], bg[j], acc[i][j], 0, 0, 0);
    }

    // epilogue: scale by invnorm, per-(b, mtile) max.  C/D: row=quad*4+r, col=l15
    float invn[4][4];
    #pragma unroll
    for (int i = 0; i < 4; ++i)
        #pragma unroll
        for (int r = 0; r < 4; ++r)
            invn[i][r] = inv_norm[m0 + wm * 64 + i * 16 + quad * 4 + r];

    #pragma unroll
    for (int j = 0; j < 4; ++j) {
        uint32_t best = 0u;
        #pragma unroll
        for (int i = 0; i < 4; ++i)
            #pragma unroll
            for (int r = 0; r < 4; ++r) {
                uint32_t k = f32_order(acc[i][j][r] * invn[i][r]);
                best = k > best ? k : best;
            }
        atomicMax(&s_best[wb * 64 + j * 16 + l15], best);
    }
    __syncthreads();
    if (t < BB) tmax[(size_t)(b0 + t) * NTILE + blockIdx.y] = s_best[t];
}

// ---------------- kernel 2b: fallback (raw fp32, inline convert) — proven R5 path ----------------
__global__ __launch_bounds__(256) void score_phase1_raw(const void* __restrict__ ctxv,
                                                        const void* __restrict__ memv,
                                                        const uint32_t* __restrict__ flag,
                                                        uint32_t* __restrict__ tmax) {
    __shared__ __align__(16) uint16_t at[BM][LDSPAD];
    __shared__ __align__(16) uint16_t bt[BB][LDSPAD];
    __shared__ uint32_t s_best[BB];
    __shared__ float s_nsq[BM];

    const int t    = threadIdx.x;
    const int b0   = blockIdx.x * BB;
    const int m0   = blockIdx.y * BM;
    const int lane = t & 63;
    const int w    = t >> 6;
    const int wm   = w >> 1;
    const int wb   = w & 1;
    const int quad = lane >> 4;
    const int l15  = lane & 15;
    const int srow = t >> 2;
    const int scol = (t & 3) * 8;

    if (t < BB) s_best[t] = 0u;

    floatx4 acc[4][4];
    #pragma unroll
    for (int i = 0; i < 4; ++i)
        #pragma unroll
        for (int j = 0; j < 4; ++j)
            acc[i][j] = (floatx4){0.f, 0.f, 0.f, 0.f};

    float nsq0 = 0.f, nsq1 = 0.f;
    const bool isbf = (*flag != 0u);

    for (int k0 = 0; k0 < D_DIM; k0 += BK) {
        __syncthreads();
        if (isbf) {
            const uint16_t* mp = (const uint16_t*)memv;
            const uint16_t* cp = (const uint16_t*)ctxv;
            uint4 va0 = *(const uint4*)(mp + (size_t)(m0 + srow) * D_DIM + k0 + scol);
            uint4 va1 = *(const uint4*)(mp + (size_t)(m0 + srow + 64) * D_DIM + k0 + scol);
            uint4 vb0 = *(const uint4*)(cp + (size_t)(b0 + srow) * D_DIM + k0 + scol);
            uint4 vb1 = *(const uint4*)(cp + (size_t)(b0 + srow + 64) * D_DIM + k0 + scol);
            *(uint4*)&at[srow][scol] = va0;
            *(uint4*)&at[srow + 64][scol] = va1;
            *(uint4*)&bt[srow][scol] = vb0;
            *(uint4*)&bt[srow + 64][scol] = vb1;
            uint32_t wa0[4] = {va0.x, va0.y, va0.z, va0.w};
            uint32_t wa1[4] = {va1.x, va1.y, va1.z, va1.w};
            #pragma unroll
            for (int i = 0; i < 4; ++i) {
                float a = __uint_as_float(wa0[i] << 16);
                float b = __uint_as_float(wa0[i] & 0xFFFF0000u);
                nsq0 = fmaf(a, a, nsq0); nsq0 = fmaf(b, b, nsq0);
                float c = __uint_as_float(wa1[i] << 16);
                float d = __uint_as_float(wa1[i] & 0xFFFF0000u);
                nsq1 = fmaf(c, c, nsq1); nsq1 = fmaf(d, d, nsq1);
            }
        } else {
            const float* mp = (const float*)memv;
            const float* cp = (const float*)ctxv;
            const float4* pa0 = (const float4*)(mp + (size_t)(m0 + srow) * D_DIM + k0 + scol);
            const float4* pa1 = (const float4*)(mp + (size_t)(m0 + srow + 64) * D_DIM + k0 + scol);
            const float4* pb0 = (const float4*)(cp + (size_t)(b0 + srow) * D_DIM + k0 + scol);
            const float4* pb1 = (const float4*)(cp + (size_t)(b0 + srow + 64) * D_DIM + k0 + scol);
            float4 a0 = pa0[0], a1 = pa0[1], a2 = pa1[0], a3 = pa1[1];
            float4 c0 = pb0[0], c1 = pb0[1], c2 = pb1[0], c3 = pb1[1];
            uint4 va0 = {pack_bf16_rtn(a0.x, a0.y), pack_bf16_rtn(a0.z, a0.w),
                         pack_bf16_rtn(a1.x, a1.y), pack_bf16_rtn(a1.z, a1.w)};
            uint4 va1 = {pack_bf16_rtn(a2.x, a2.y), pack_bf16_rtn(a2.z, a2.w),
                         pack_bf16_rtn(a3.x, a3.y), pack_bf16_rtn(a3.z, a3.w)};
            uint4 vb0 = {pack_bf16_rtn(c0.x, c0.y), pack_bf16_rtn(c0.z, c0.w),
                         pack_bf16_rtn(c1.x, c1.y), pack_bf16_rtn(c1.z, c1.w)};
            uint4 vb1 = {pack_bf16_rtn(c2.x, c2.y), pack_bf16_rtn(c2.z, c2.w),
                         pack_bf16_rtn(c3.x, c3.y), pack_bf16_rtn(c3.z, c3.w)};
            *(uint4*)&at[srow][scol] = va0;
            *(uint4*)&at[srow + 64][scol] = va1;
            *(uint4*)&bt[srow][scol] = vb0;
            *(uint4*)&bt[srow + 64][scol] = vb1;
            nsq0 = fmaf(a0.x, a0.x, nsq0); nsq0 = fmaf(a0.y, a0.y, nsq0);
            nsq0 = fmaf(a0.z, a0.z, nsq0); nsq0 = fmaf(a0.w, a0.w, nsq0);
            nsq0 = fmaf(a1.x, a1.x, nsq0); nsq0 = fmaf(a1.y, a1.y, nsq0);
            nsq0 = fmaf(a1.z, a1.z, nsq0); nsq0 = fmaf(a1.w, a1.w, nsq0);
            nsq1 = fmaf(a2.x, a2.x, nsq1); nsq1 = fmaf(a2.y, a2.y, nsq1);
            nsq1 = fmaf(a2.z, a2.z, nsq1); nsq1 = fmaf(a2.w, a2.w, nsq1);
            nsq1 = fmaf(a3.x, a3.x, nsq1); nsq1 = fmaf(a3.y, a3.y, nsq1);
            nsq1 = fmaf(a3.z, a3.z, nsq1); nsq1 = fmaf(a3.w, a3.w, nsq1);
        }
        __syncthreads();

        short8 af[4], bg[4];
        #pragma unroll
        for (int i = 0; i < 4; ++i)
            af[i] = *(const short8*)&at[wm * 64 + i * 16 + l15][quad * 8];
        #pragma unroll
        for (int j = 0; j < 4; ++j)
            bg[j] = *(const short8*)&bt[wb * 64 + j * 16 + l15][quad * 8];

        #pragma unroll
        for (int i = 0; i < 4; ++i)
            #pragma unroll
            for (int j = 0; j < 4; ++j)
                acc[i][j] = __builtin_amdgcn_mfma_f32_16x16x32_bf16(af[i], bg[j], acc[i][j], 0, 0, 0);
    }

    nsq0 += __shfl_xor(nsq0, 1, 64); nsq0 += __shfl_xor(nsq0, 2, 64);
    nsq1 += __shfl_xor(nsq1, 1, 64); nsq1 += __shfl_xor(nsq1, 2, 64);
    __syncthreads();
    if ((t & 3) == 0) { s_nsq[srow] = nsq0; s_nsq[srow + 64] = nsq1; }
    __syncthreads();

    float invn[4][4];
    #pragma unroll
    for (int i = 0; i < 4; ++i)
        #pragma unroll
        for (int r = 0; r < 4; ++r)
            invn[i][r] = rsqrtf(fmaxf(s_nsq[wm * 64 + i * 16 + quad * 4 + r], 1e-12f));

    #pragma unroll
    for (int j = 0; j < 4; ++j) {
        uint32_t best = 0u;
        #pragma unroll
        for (int i = 0; i < 4; ++i)
            #pragma unroll
            for (int r = 0; r < 4; ++r) {
                uint32_t k = f32_order(acc[i][j][r] * invn[i][r]);
                best = k > best ? k : best;
            }
        atomicMax(&s_best[wb * 64 + j * 16 + l15], best);
    }
    __syncthreads();
    if (t < BB) tmax[(size_t)(b0 + t) * NTILE + blockIdx.y] = s_best[t];
}

// ---------------- kernel 3: exact fp64 rescore (no sqrt/div) + gather ----------------
__global__ __launch_bounds__(256) void phase2(const void* __restrict__ ctxv,
                                              const void* __restrict__ memv,
                                              const uint32_t* __restrict__ flag,
                                              const uint32_t* __restrict__ tmax,
                                              void* __restrict__ outv) {
    __shared__ float s_ctx[D_DIM];
    __shared__ int s_list[NTILE];
    __shared__ int s_cnt;
    __shared__ uint32_t s_red[4];
    __shared__ float s_cn[4];
    __shared__ double s_d[4], s_n[4];
    __shared__ int s_m[4];
    __shared__ int s_bestm;

    const int b = blockIdx.x;
    const int t = threadIdx.x;
    const int lane = t & 63;
    const int w = t >> 6;
    const bool isbf = (*flag != 0u);

    if (t == 0) s_cnt = 0;
    if (isbf) {
        if (t < 64) {
            uint4 v = *((const uint4*)((const uint16_t*)ctxv + (size_t)b * D_DIM) + t);
            uint32_t ww[4] = {v.x, v.y, v.z, v.w};
            #pragma unroll
            for (int i = 0; i < 4; ++i) {
                s_ctx[t * 8 + 2 * i]     = __uint_as_float(ww[i] << 16);
                s_ctx[t * 8 + 2 * i + 1] = __uint_as_float(ww[i] & 0xFFFF0000u);
            }
        }
    } else {
        if (t < 128)
            ((float4*)s_ctx)[t] = ((const float4*)((const float*)ctxv + (size_t)b * D_DIM))[t];
    }
    __syncthreads();

    // ctx norm (scale-invariant rescan margin)
    float cs = s_ctx[t] * s_ctx[t] + s_ctx[t + 256] * s_ctx[t + 256];
    #pragma unroll
    for (int o = 32; o; o >>= 1) cs += __shfl_xor(cs, o, 64);
    if (lane == 0) s_cn[w] = cs;

    // block max over this b's 512 tile keys
    const uint32_t* tk = tmax + (size_t)b * NTILE;
    uint32_t k0 = tk[t], k1 = tk[t + 256];
    uint32_t km = k0 > k1 ? k0 : k1;
    #pragma unroll
    for (int o = 32; o; o >>= 1) { uint32_t ot = __shfl_xor(km, o, 64); km = ot > km ? ot : km; }
    if (lane == 0) s_red[w] = km;
    __syncthreads();
    uint32_t kbest = s_red[0];
    #pragma unroll
    for (int i = 1; i < 4; ++i) kbest = s_red[i] > kbest ? s_red[i] : kbest;
    const float cnorm = sqrtf(s_cn[0] + s_cn[1] + s_cn[2] + s_cn[3]);
    const uint32_t keyT = f32_order(f32_unorder(kbest) - DELTA_COS * cnorm);

    if (k0 >= keyT) { int idx = atomicAdd(&s_cnt, 1); s_list[idx] = t; }
    if (k1 >= keyT) { int idx = atomicAdd(&s_cnt, 1); s_list[idx] = t + 256; }
    __syncthreads();
    const int total = s_cnt * BM;

    // best = (dot, nsq, m); compare via signed-square cross-multiplication:
    // s_a > s_b  <=>  dot_a*|dot_a|*nsq_b > dot_b*|dot_b|*nsq_a   (nsq > 0)
    double bd = -1.0e300, bn = 1.0;
    double bp = bd * 1.0e300;   // -inf: any real row wins the first compare
    int bm = 0x7FFFFFFF;
    const float* cb = s_ctx + lane * 8;

    for (int base = w * 2; base < total; base += 8) {
        const bool has1 = (base + 1 < total);
        const int ia = base, ib = has1 ? base + 1 : base;
        const int ma = s_list[ia >> 7] * BM + (ia & 127);
        const int mb = s_list[ib >> 7] * BM + (ib & 127);
        double d0 = 0.0, n0 = 0.0, d1 = 0.0, n1 = 0.0;
        if (isbf) {
            uint4 va = *((const uint4*)((const uint16_t*)memv + (size_t)ma * D_DIM) + lane);
            uint4 vb = *((const uint4*)((const uint16_t*)memv + (size_t)mb * D_DIM) + lane);
            uint32_t wa[4] = {va.x, va.y, va.z, va.w};
            uint32_t wbv[4] = {vb.x, vb.y, vb.z, vb.w};
            #pragma unroll
            for (int i = 0; i < 4; ++i) {
                float a0 = __uint_as_float(wa[i] << 16);
                float a1 = __uint_as_float(wa[i] & 0xFFFF0000u);
                d0 += (double)a0 * (double)cb[2 * i];
                d0 += (double)a1 * (double)cb[2 * i + 1];
                n0 += (double)a0 * (double)a0 + (double)a1 * (double)a1;
                float b0v = __uint_as_float(wbv[i] << 16);
                float b1v = __uint_as_float(wbv[i] & 0xFFFF0000u);
                d1 += (double)b0v * (double)cb[2 * i];
                d1 += (double)b1v * (double)cb[2 * i + 1];
                n1 += (double)b0v * (double)b0v + (double)b1v * (double)b1v;
            }
        } else {
            const float4* pa = (const float4*)((const float*)memv + (size_t)ma * D_DIM) + lane * 2;
            const float4* pb = (const float4*)((const float*)memv + (size_t)mb * D_DIM) + lane * 2;
            float4 a0 = pa[0], a1 = pa[1], b0v = pb[0], b1v = pb[1];
            float xa[8] = {a0.x, a0.y, a0.z, a0.w, a1.x, a1.y, a1.z, a1.w};
            float xb[8] = {b0v.x, b0v.y, b0v.z, b0v.w, b1v.x, b1v.y, b1v.z, b1v.w};
            #pragma unroll
            for (int i = 0; i < 8; ++i) {
                d0 += (double)xa[i] * (double)cb[i];
                n0 += (double)xa[i] * (double)xa[i];
                d1 += (double)xb[i] * (double)cb[i];
                n1 += (double)xb[i] * (double)xb[i];
            }
        }
        #pragma unroll
        for (int o = 32; o; o >>= 1) {
            d0 += __shfl_xor(d0, o, 64);
            n0 += __shfl_xor(n0, o, 64);
            d1 += __shfl_xor(d1, o, 64);
            n1 += __shfl_xor(n1, o, 64);
        }
        double p0 = d0 * fabs(d0);
        double lhs = p0 * bn, rhs = bp * n0;
        if (lhs > rhs || (lhs == rhs && ma < bm)) { bd = d0; bn = n0; bp = p0; bm = ma; }
        if (has1) {
            double p1 = d1 * fabs(d1);
            double lhs1 = p1 * bn, rhs1 = bp * n1;
            if (lhs1 > rhs1 || (lhs1 == rhs1 && mb < bm)) { bd = d1; bn = n1; bp = p1; bm = mb; }
        }
    }
    if (lane == 0) { s_d[w] = bd; s_n[w] = bn; s_m[w] = bm; }
    __syncthreads();
    if (t == 0) {
        double cd = s_d[0], cn2 = s_n[0], cp = cd * fabs(cd);
        int cm = s_m[0];
        #pragma unroll
        for (int i = 1; i < 4; ++i) {
            double pd = s_d[i], pn = s_n[i], pp = pd * fabs(pd);
            double lhs = pp * cn2, rhs = cp * pn;
            if (lhs > rhs || (lhs == rhs && s_m[i] < cm)) { cd = pd; cn2 = pn; cp = pp; cm = s_m[i]; }
        }
        s_bestm = cm;
    }
    __syncthreads();
    const int mbest = s_bestm;
    if (isbf) {
        if (t < 64)
            ((uint4*)((uint16_t*)outv + (size_t)b * D_DIM))[t] =
                ((const uint4*)((const uint16_t*)memv + (size_t)mbest * D_DIM))[t];
    } else {
        if (t < 128)
            ((float4*)((float*)outv + (size_t)b * D_DIM))[t] =
                ((const float4*)((const float*)memv + (size_t)mbest * D_DIM))[t];
    }
}

extern "C" void kernel_launch(void* const* d_in, const int* in_sizes, int n_in,
                              void* d_out, int out_size, void* d_ws, size_t ws_size,
                              hipStream_t stream) {
    const void* ctx = d_in[0];
    const void* mem = d_in[1];
    if (in_sizes[0] > in_sizes[1]) { ctx = d_in[1]; mem = d_in[0]; }  // ctx is smaller

    // preferred ws layout (needs ~69 MB):
    const size_t MEMBF_OFF = 0;                      // 67,108,864 B
    const size_t CTXBF_OFF = 67108864;               //    524,288 B
    const size_t INV_OFF   = 67633152;               //    262,144 B
    const size_t TMAX_OFF  = 67895296;               //  1,048,576 B
    const size_t FLAG_OFF  = 68943872;
    const size_t NEED      = FLAG_OFF + 256;

    dim3 grid(B_CTX / BB, M_MEM / BM);
    if (ws_size >= NEED) {
        uint4*    mem_bf   = (uint4*)((char*)d_ws + MEMBF_OFF);
        uint4*    ctx_bf   = (uint4*)((char*)d_ws + CTXBF_OFF);
        float*    inv_norm = (float*)((char*)d_ws + INV_OFF);
        uint32_t* tmax     = (uint32_t*)((char*)d_ws + TMAX_OFF);
        uint32_t* flag     = (uint32_t*)((char*)d_ws + FLAG_OFF);
        detect_init<<<1, 64, 0, stream>>>((const uint32_t*)mem, flag);
        convert_norms<<<(M_MEM + B_CTX) / 4, 256, 0, stream>>>(mem, ctx, flag, mem_bf, ctx_bf, inv_norm);
        score_phase1_pre<<<grid, 256, 0, stream>>>(ctx, mem, (const uint16_t*)ctx_bf,
                                                   (const uint16_t*)mem_bf, flag, inv_norm, tmax);
        phase2<<<B_CTX, 256, 0, stream>>>(ctx, mem, flag, tmax, d_out);
    } else {
        // fallback: R5 layout + inline-convert phase1
        uint32_t* tmax = (uint32_t*)d_ws;
        uint32_t* flag = (uint32_t*)((char*)d_ws + (size_t)B_CTX * NTILE * 4);
        detect_init<<<1, 64, 0, stream>>>((const uint32_t*)mem, flag);
        score_phase1_raw<<<grid, 256, 0, stream>>>(ctx, mem, flag, tmax);
        phase2<<<B_CTX, 256, 0, stream>>>(ctx, mem, flag, tmax, d_out);
    }
}

// Round 7
// 269.431 us; speedup vs baseline: 1.3429x; 1.3141x over previous
//
#include <hip/hip_runtime.h>
#include <hip/hip_bf16.h>
#include <stdint.h>

#define D_DIM 512
#define B_CTX 512
#define M_MEM 65536
#define BM 128
#define BB 128
#define BK 32
#define LDSPAD 40            // 80 B row pitch: 16B-aligned, frag reads 2-way (free)
#define DELTA_COS 2.5e-3f    // ~35 sigma of bf16 cosine noise, scale-invariant
#define LISTCAP 2048

typedef __attribute__((ext_vector_type(8))) short short8;   // 8 bf16 (4 VGPR)
typedef __attribute__((ext_vector_type(4))) float floatx4;  // MFMA accumulator

__device__ __forceinline__ uint32_t f32_order(float s) {    // monotone f32->u32
    uint32_t u = __float_as_uint(s);
    return (u & 0x80000000u) ? ~u : (u | 0x80000000u);
}
__device__ __forceinline__ float f32_unorder(uint32_t v) {
    uint32_t u = (v & 0x80000000u) ? (v & 0x7FFFFFFFu) : ~v;
    return __uint_as_float(u);
}
__device__ __forceinline__ uint32_t pack_bf16_rtn(float a, float b) {
    uint32_t ua = __float_as_uint(a) + 0x8000u;
    uint32_t ub = __float_as_uint(b) + 0x8000u;
    return (ua >> 16) | (ub & 0xFFFF0000u);
}

// ---------------- kernel 0: dtype probe ----------------
__global__ void detect_init(const uint32_t* __restrict__ mem_raw,
                            uint32_t* __restrict__ flag) {
    __shared__ int cnt;
    if (threadIdx.x == 0) cnt = 0;
    __syncthreads();
    int s = 0;
    #pragma unroll
    for (int i = 0; i < 8; ++i) {
        uint32_t u = mem_raw[threadIdx.x * 8 + i];
        uint32_t e = (u >> 7) & 0xFFu;   // exponent of LOW bf16 half
        s += (e >= 96u && e <= 144u) ? 1 : 0;
    }
    atomicAdd(&cnt, s);
    __syncthreads();
    if (threadIdx.x == 0) *flag = (cnt > 256) ? 1u : 0u;   // 1 == bf16 inputs
}

// ---- kernel 1: bf16 MFMA scores + per-(b, 16-row-group) max (inline convert) ----
__global__ __launch_bounds__(256) void score_phase1(const void* __restrict__ ctxv,
                                                    const void* __restrict__ memv,
                                                    const uint32_t* __restrict__ flag,
                                                    uint32_t* __restrict__ tmax,
                                                    int coarse) {
    __shared__ __align__(16) uint16_t at[BM][LDSPAD];
    __shared__ __align__(16) uint16_t bt[BB][LDSPAD];
    __shared__ float s_nsq[BM];
    __shared__ uint32_t s_gbest[8][BB];   // per (16-row group, col) max

    const int t    = threadIdx.x;
    const int b0   = blockIdx.x * BB;
    const int m0   = blockIdx.y * BM;
    const int lane = t & 63;
    const int w    = t >> 6;
    const int wm   = w >> 1;
    const int wb   = w & 1;
    const int quad = lane >> 4;
    const int l15  = lane & 15;
    const int srow = t >> 2;
    const int scol = (t & 3) * 8;

    floatx4 acc[4][4];
    #pragma unroll
    for (int i = 0; i < 4; ++i)
        #pragma unroll
        for (int j = 0; j < 4; ++j)
            acc[i][j] = (floatx4){0.f, 0.f, 0.f, 0.f};

    float nsq0 = 0.f, nsq1 = 0.f;
    const bool isbf = (*flag != 0u);

    for (int k0 = 0; k0 < D_DIM; k0 += BK) {
        __syncthreads();
        if (isbf) {
            const uint16_t* mp = (const uint16_t*)memv;
            const uint16_t* cp = (const uint16_t*)ctxv;
            uint4 va0 = *(const uint4*)(mp + (size_t)(m0 + srow) * D_DIM + k0 + scol);
            uint4 va1 = *(const uint4*)(mp + (size_t)(m0 + srow + 64) * D_DIM + k0 + scol);
            uint4 vb0 = *(const uint4*)(cp + (size_t)(b0 + srow) * D_DIM + k0 + scol);
            uint4 vb1 = *(const uint4*)(cp + (size_t)(b0 + srow + 64) * D_DIM + k0 + scol);
            *(uint4*)&at[srow][scol] = va0;
            *(uint4*)&at[srow + 64][scol] = va1;
            *(uint4*)&bt[srow][scol] = vb0;
            *(uint4*)&bt[srow + 64][scol] = vb1;
            uint32_t wa0[4] = {va0.x, va0.y, va0.z, va0.w};
            uint32_t wa1[4] = {va1.x, va1.y, va1.z, va1.w};
            #pragma unroll
            for (int i = 0; i < 4; ++i) {
                float a = __uint_as_float(wa0[i] << 16);
                float b = __uint_as_float(wa0[i] & 0xFFFF0000u);
                nsq0 = fmaf(a, a, nsq0); nsq0 = fmaf(b, b, nsq0);
                float c = __uint_as_float(wa1[i] << 16);
                float d = __uint_as_float(wa1[i] & 0xFFFF0000u);
                nsq1 = fmaf(c, c, nsq1); nsq1 = fmaf(d, d, nsq1);
            }
        } else {
            const float* mp = (const float*)memv;
            const float* cp = (const float*)ctxv;
            const float4* pa0 = (const float4*)(mp + (size_t)(m0 + srow) * D_DIM + k0 + scol);
            const float4* pa1 = (const float4*)(mp + (size_t)(m0 + srow + 64) * D_DIM + k0 + scol);
            const float4* pb0 = (const float4*)(cp + (size_t)(b0 + srow) * D_DIM + k0 + scol);
            const float4* pb1 = (const float4*)(cp + (size_t)(b0 + srow + 64) * D_DIM + k0 + scol);
            float4 a0 = pa0[0], a1 = pa0[1], a2 = pa1[0], a3 = pa1[1];
            float4 c0 = pb0[0], c1 = pb0[1], c2 = pb1[0], c3 = pb1[1];
            uint4 va0 = {pack_bf16_rtn(a0.x, a0.y), pack_bf16_rtn(a0.z, a0.w),
                         pack_bf16_rtn(a1.x, a1.y), pack_bf16_rtn(a1.z, a1.w)};
            uint4 va1 = {pack_bf16_rtn(a2.x, a2.y), pack_bf16_rtn(a2.z, a2.w),
                         pack_bf16_rtn(a3.x, a3.y), pack_bf16_rtn(a3.z, a3.w)};
            uint4 vb0 = {pack_bf16_rtn(c0.x, c0.y), pack_bf16_rtn(c0.z, c0.w),
                         pack_bf16_rtn(c1.x, c1.y), pack_bf16_rtn(c1.z, c1.w)};
            uint4 vb1 = {pack_bf16_rtn(c2.x, c2.y), pack_bf16_rtn(c2.z, c2.w),
                         pack_bf16_rtn(c3.x, c3.y), pack_bf16_rtn(c3.z, c3.w)};
            *(uint4*)&at[srow][scol] = va0;
            *(uint4*)&at[srow + 64][scol] = va1;
            *(uint4*)&bt[srow][scol] = vb0;
            *(uint4*)&bt[srow + 64][scol] = vb1;
            nsq0 = fmaf(a0.x, a0.x, nsq0); nsq0 = fmaf(a0.y, a0.y, nsq0);
            nsq0 = fmaf(a0.z, a0.z, nsq0); nsq0 = fmaf(a0.w, a0.w, nsq0);
            nsq0 = fmaf(a1.x, a1.x, nsq0); nsq0 = fmaf(a1.y, a1.y, nsq0);
            nsq0 = fmaf(a1.z, a1.z, nsq0); nsq0 = fmaf(a1.w, a1.w, nsq0);
            nsq1 = fmaf(a2.x, a2.x, nsq1); nsq1 = fmaf(a2.y, a2.y, nsq1);
            nsq1 = fmaf(a2.z, a2.z, nsq1); nsq1 = fmaf(a2.w, a2.w, nsq1);
            nsq1 = fmaf(a3.x, a3.x, nsq1); nsq1 = fmaf(a3.y, a3.y, nsq1);
            nsq1 = fmaf(a3.z, a3.z, nsq1); nsq1 = fmaf(a3.w, a3.w, nsq1);
        }
        __syncthreads();

        short8 af[4], bg[4];
        #pragma unroll
        for (int i = 0; i < 4; ++i)
            af[i] = *(const short8*)&at[wm * 64 + i * 16 + l15][quad * 8];
        #pragma unroll
        for (int j = 0; j < 4; ++j)
            bg[j] = *(const short8*)&bt[wb * 64 + j * 16 + l15][quad * 8];

        #pragma unroll
        for (int i = 0; i < 4; ++i)
            #pragma unroll
            for (int j = 0; j < 4; ++j)
                acc[i][j] = __builtin_amdgcn_mfma_f32_16x16x32_bf16(af[i], bg[j], acc[i][j], 0, 0, 0);
    }

    nsq0 += __shfl_xor(nsq0, 1, 64); nsq0 += __shfl_xor(nsq0, 2, 64);
    nsq1 += __shfl_xor(nsq1, 1, 64); nsq1 += __shfl_xor(nsq1, 2, 64);
    __syncthreads();
    if ((t & 3) == 0) { s_nsq[srow] = nsq0; s_nsq[srow + 64] = nsq1; }
    __syncthreads();

    float invn[4][4];
    #pragma unroll
    for (int i = 0; i < 4; ++i)
        #pragma unroll
        for (int r = 0; r < 4; ++r)
            invn[i][r] = rsqrtf(fmaxf(s_nsq[wm * 64 + i * 16 + quad * 4 + r], 1e-12f));

    // group epilogue: frag i == 16-row group (wm*4+i). Cross-quad shuffle, no atomics.
    #pragma unroll
    for (int i = 0; i < 4; ++i)
        #pragma unroll
        for (int j = 0; j < 4; ++j) {
            uint32_t k = 0;
            #pragma unroll
            for (int r = 0; r < 4; ++r) {
                uint32_t kk = f32_order(acc[i][j][r] * invn[i][r]);
                k = kk > k ? kk : k;
            }
            uint32_t o1 = __shfl_xor(k, 16, 64); k = o1 > k ? o1 : k;
            uint32_t o2 = __shfl_xor(k, 32, 64); k = o2 > k ? o2 : k;
            if (quad == 0) s_gbest[wm * 4 + i][wb * 64 + j * 16 + l15] = k;
        }
    __syncthreads();

    if (!coarse) {
        const int G0 = blockIdx.y * 8;
        for (int e = t; e < 8 * BB; e += 256) {
            const int col = e >> 3, g = e & 7;
            tmax[(size_t)(b0 + col) * 4096 + G0 + g] = s_gbest[g][col];
        }
    } else {
        if (t < BB) {
            uint32_t k = s_gbest[0][t];
            #pragma unroll
            for (int g = 1; g < 8; ++g) k = s_gbest[g][t] > k ? s_gbest[g][t] : k;
            tmax[(size_t)(b0 + t) * 512 + blockIdx.y] = k;
        }
    }
}

// ---------------- kernel 2: exact fp64 rescore of candidate groups + gather ----------------
__global__ __launch_bounds__(256) void phase2(const void* __restrict__ ctxv,
                                              const void* __restrict__ memv,
                                              const uint32_t* __restrict__ flag,
                                              const uint32_t* __restrict__ tmax,
                                              void* __restrict__ outv,
                                              int ngrp, int gshift) {
    __shared__ float s_ctx[D_DIM];
    __shared__ int s_list[LISTCAP];
    __shared__ int s_cnt;
    __shared__ uint32_t s_red[4];
    __shared__ float s_cn[4];
    __shared__ double s_d[4], s_n[4];
    __shared__ int s_m[4];
    __shared__ int s_bestm;

    const int b = blockIdx.x;
    const int t = threadIdx.x;
    const int lane = t & 63;
    const int w = t >> 6;
    const bool isbf = (*flag != 0u);
    const int gsize = 1 << gshift, gmask = gsize - 1;

    if (t == 0) s_cnt = 0;
    if (isbf) {
        if (t < 64) {
            uint4 v = *((const uint4*)((const uint16_t*)ctxv + (size_t)b * D_DIM) + t);
            uint32_t ww[4] = {v.x, v.y, v.z, v.w};
            #pragma unroll
            for (int i = 0; i < 4; ++i) {
                s_ctx[t * 8 + 2 * i]     = __uint_as_float(ww[i] << 16);
                s_ctx[t * 8 + 2 * i + 1] = __uint_as_float(ww[i] & 0xFFFF0000u);
            }
        }
    } else {
        if (t < 128)
            ((float4*)s_ctx)[t] = ((const float4*)((const float*)ctxv + (size_t)b * D_DIM))[t];
    }
    __syncthreads();

    // ctx norm (scale-invariant rescan margin)
    float cs = s_ctx[t] * s_ctx[t] + s_ctx[t + 256] * s_ctx[t + 256];
    #pragma unroll
    for (int o = 32; o; o >>= 1) cs += __shfl_xor(cs, o, 64);
    if (lane == 0) s_cn[w] = cs;

    // scan this b's group keys (coalesced), find block max
    const uint32_t* tk = tmax + (size_t)b * ngrp;
    const int nk = ngrp >> 8;          // 16 (fine) or 2 (coarse)
    uint32_t kv[16];
    uint32_t km = 0;
    for (int i = 0; i < nk; ++i) {
        kv[i] = tk[t + (i << 8)];
        km = kv[i] > km ? kv[i] : km;
    }
    #pragma unroll
    for (int o = 32; o; o >>= 1) { uint32_t ot = __shfl_xor(km, o, 64); km = ot > km ? ot : km; }
    if (lane == 0) s_red[w] = km;
    __syncthreads();
    uint32_t kbest = s_red[0];
    #pragma unroll
    for (int i = 1; i < 4; ++i) kbest = s_red[i] > kbest ? s_red[i] : kbest;
    const float cnorm = sqrtf(s_cn[0] + s_cn[1] + s_cn[2] + s_cn[3]);
    const uint32_t keyT = f32_order(f32_unorder(kbest) - DELTA_COS * cnorm);

    for (int i = 0; i < nk; ++i)
        if (kv[i] >= keyT) {
            int idx = atomicAdd(&s_cnt, 1);
            if (idx < LISTCAP) s_list[idx] = t + (i << 8);
        }
    __syncthreads();
    int cnt = s_cnt; if (cnt > LISTCAP) cnt = LISTCAP;
    const int total = cnt << gshift;

    // best = (dot, nsq, m); compare via signed-square cross-multiplication
    double bd = -1.0e300, bn = 1.0;
    double bp = bd * 1.0e300;   // -inf
    int bm = 0x7FFFFFFF;
    const float* cb = s_ctx + lane * 8;

    for (int base = w * 2; base < total; base += 8) {
        const bool has1 = (base + 1 < total);
        const int ia = base, ib = has1 ? base + 1 : base;
        const int ma = (s_list[ia >> gshift] << gshift) + (ia & gmask);
        const int mb = (s_list[ib >> gshift] << gshift) + (ib & gmask);
        double d0 = 0.0, n0 = 0.0, d1 = 0.0, n1 = 0.0;
        if (isbf) {
            uint4 va = *((const uint4*)((const uint16_t*)memv + (size_t)ma * D_DIM) + lane);
            uint4 vb = *((const uint4*)((const uint16_t*)memv + (size_t)mb * D_DIM) + lane);
            uint32_t wa[4] = {va.x, va.y, va.z, va.w};
            uint32_t wbv[4] = {vb.x, vb.y, vb.z, vb.w};
            #pragma unroll
            for (int i = 0; i < 4; ++i) {
                float a0 = __uint_as_float(wa[i] << 16);
                float a1 = __uint_as_float(wa[i] & 0xFFFF0000u);
                d0 += (double)a0 * (double)cb[2 * i];
                d0 += (double)a1 * (double)cb[2 * i + 1];
                n0 += (double)a0 * (double)a0 + (double)a1 * (double)a1;
                float b0v = __uint_as_float(wbv[i] << 16);
                float b1v = __uint_as_float(wbv[i] & 0xFFFF0000u);
                d1 += (double)b0v * (double)cb[2 * i];
                d1 += (double)b1v * (double)cb[2 * i + 1];
                n1 += (double)b0v * (double)b0v + (double)b1v * (double)b1v;
            }
        } else {
            const float4* pa = (const float4*)((const float*)memv + (size_t)ma * D_DIM) + lane * 2;
            const float4* pb = (const float4*)((const float*)memv + (size_t)mb * D_DIM) + lane * 2;
            float4 a0 = pa[0], a1 = pa[1], b0v = pb[0], b1v = pb[1];
            float xa[8] = {a0.x, a0.y, a0.z, a0.w, a1.x, a1.y, a1.z, a1.w};
            float xb[8] = {b0v.x, b0v.y, b0v.z, b0v.w, b1v.x, b1v.y, b1v.z, b1v.w};
            #pragma unroll
            for (int i = 0; i < 8; ++i) {
                d0 += (double)xa[i] * (double)cb[i];
                n0 += (double)xa[i] * (double)xa[i];
                d1 += (double)xb[i] * (double)cb[i];
                n1 += (double)xb[i] * (double)xb[i];
            }
        }
        #pragma unroll
        for (int o = 32; o; o >>= 1) {
            d0 += __shfl_xor(d0, o, 64);
            n0 += __shfl_xor(n0, o, 64);
            d1 += __shfl_xor(d1, o, 64);
            n1 += __shfl_xor(n1, o, 64);
        }
        double p0 = d0 * fabs(d0);
        double lhs = p0 * bn, rhs = bp * n0;
        if (lhs > rhs || (lhs == rhs && ma < bm)) { bd = d0; bn = n0; bp = p0; bm = ma; }
        if (has1) {
            double p1 = d1 * fabs(d1);
            double lhs1 = p1 * bn, rhs1 = bp * n1;
            if (lhs1 > rhs1 || (lhs1 == rhs1 && mb < bm)) { bd = d1; bn = n1; bp = p1; bm = mb; }
        }
    }
    if (lane == 0) { s_d[w] = bd; s_n[w] = bn; s_m[w] = bm; }
    __syncthreads();
    if (t == 0) {
        double cd = s_d[0], cn2 = s_n[0], cp = cd * fabs(cd);
        int cm = s_m[0];
        #pragma unroll
        for (int i = 1; i < 4; ++i) {
            double pd = s_d[i], pn = s_n[i], pp = pd * fabs(pd);
            double lhs = pp * cn2, rhs = cp * pn;
            if (lhs > rhs || (lhs == rhs && s_m[i] < cm)) { cd = pd; cn2 = pn; cp = pp; cm = s_m[i]; }
        }
        s_bestm = cm;
    }
    __syncthreads();
    const int mbest = s_bestm;
    if (isbf) {
        if (t < 64)
            ((uint4*)((uint16_t*)outv + (size_t)b * D_DIM))[t] =
                ((const uint4*)((const uint16_t*)memv + (size_t)mbest * D_DIM))[t];
    } else {
        if (t < 128)
            ((float4*)((float*)outv + (size_t)b * D_DIM))[t] =
                ((const float4*)((const float*)memv + (size_t)mbest * D_DIM))[t];
    }
}

extern "C" void kernel_launch(void* const* d_in, const int* in_sizes, int n_in,
                              void* d_out, int out_size, void* d_ws, size_t ws_size,
                              hipStream_t stream) {
    const void* ctx = d_in[0];
    const void* mem = d_in[1];
    if (in_sizes[0] > in_sizes[1]) { ctx = d_in[1]; mem = d_in[0]; }  // ctx is smaller

    const size_t fineBytes   = (size_t)B_CTX * 4096 * 4;   // 8 MB
    const size_t coarseBytes = (size_t)B_CTX * 512 * 4;    // 1 MB
    dim3 grid(B_CTX / BB, M_MEM / BM);

    if (ws_size >= fineBytes + 256) {
        uint32_t* tmax = (uint32_t*)d_ws;
        uint32_t* flag = (uint32_t*)((char*)d_ws + fineBytes);
        detect_init<<<1, 64, 0, stream>>>((const uint32_t*)mem, flag);
        score_phase1<<<grid, 256, 0, stream>>>(ctx, mem, flag, tmax, 0);
        phase2<<<B_CTX, 256, 0, stream>>>(ctx, mem, flag, tmax, d_out, 4096, 4);
    } else {
        uint32_t* tmax = (uint32_t*)d_ws;
        uint32_t* flag = (uint32_t*)((char*)d_ws + coarseBytes);
        detect_init<<<1, 64, 0, stream>>>((const uint32_t*)mem, flag);
        score_phase1<<<grid, 256, 0, stream>>>(ctx, mem, flag, tmax, 1);
        phase2<<<B_CTX, 256, 0, stream>>>(ctx, mem, flag, tmax, d_out, 512, 7);
    }
}